// Round 3
// baseline (253.439 us; speedup 1.0000x reference)
//
#include <hip/hip_runtime.h>
#include <hip/hip_bf16.h>

// Problem constants
#define BB 4
#define TT 512
#define JJ 17
#define DD 256
#define HH 8
#define MROWS (BB*TT*JJ)            // 34816 = 272 * 128
#define SZE ((size_t)MROWS * DD)    // 8,912,896 elems
#define WSZ (DD*DD)                 // 65536
#define QSCALE 0.2550265247510319f  // 32^-0.5 * log2(e)
#define RST (17*256)                // row stride of [*, j, d] tensors (4352)

typedef short v8s __attribute__((ext_vector_type(8)));   // 8 bf16 in 4 VGPRs
typedef float v4f __attribute__((ext_vector_type(4)));   // MFMA accumulator

// f32->bf16 round-to-nearest-even (accuracy-critical paths)
__device__ __forceinline__ unsigned short f2bf(float f) {
    union { float f; unsigned int u; } c; c.f = f;
    unsigned int u = c.u;
    return (unsigned short)((u + 0x7FFF + ((u >> 16) & 1)) >> 16);
}
// hot path: pack two f32 -> two bf16 (round-half-up), 2 add + 1 perm
__device__ __forceinline__ unsigned int pkbf(float lo, float hi) {
    union { float f; unsigned int u; } a, b; a.f = lo; b.f = hi;
    return __builtin_amdgcn_perm(b.u + 0x8000u, a.u + 0x8000u, 0x07060302u);
}
// bare v_exp_f32 (2^x); scores bounded, denorm P irrelevant to softmax sum.
__device__ __forceinline__ float fexp2(float x) {
    return __builtin_amdgcn_exp2f(x);
}

// async global->LDS, 16B per lane (HW: wave-uniform base + lane*16)
__device__ __forceinline__ void gld16(const unsigned short* g, unsigned short* l) {
    __builtin_amdgcn_global_load_lds(
        (const __attribute__((address_space(1))) void*)g,
        (__attribute__((address_space(3))) void*)l,
        16, 0, 0);
}

// ---------------------------------------------------------------------------
// Prep: fp32 -> bf16 (RNE). q gets QSCALE folded in (linearity of the proj).
// 8 elems/thread, exact grid cover.
// ---------------------------------------------------------------------------
__global__ __launch_bounds__(256) void prep_kernel(
    const float* __restrict__ q, const float* __restrict__ kv,
    const float* __restrict__ Wq, const float* __restrict__ Wk,
    const float* __restrict__ Wv, const float* __restrict__ Wp,
    unsigned short* __restrict__ qb, unsigned short* __restrict__ kvb,
    unsigned short* __restrict__ Wqb, unsigned short* __restrict__ Wkb,
    unsigned short* __restrict__ Wvb, unsigned short* __restrict__ Wpb)
{
    size_t i = ((size_t)blockIdx.x * 256 + threadIdx.x) * 8;
    const float* src; unsigned short* dst; size_t off; float scale = 1.f;
    if (i < SZE)            { src = q;  dst = qb;  off = i;        scale = QSCALE; }
    else if (i < 2 * SZE)   { src = kv; dst = kvb; off = i - SZE; }
    else {
        size_t k = i - 2 * SZE;
        int w = (int)(k >> 16);         // WSZ = 65536
        off = k & (WSZ - 1);
        src = (w == 0) ? Wq : (w == 1) ? Wk : (w == 2) ? Wv : Wp;
        dst = (w == 0) ? Wqb : (w == 1) ? Wkb : (w == 2) ? Wvb : Wpb;
    }
    float4 x0 = *(const float4*)(src + off);
    float4 x1 = *(const float4*)(src + off + 4);
    union { unsigned short s[8]; int4 v; } u;
    u.s[0] = f2bf(x0.x * scale); u.s[1] = f2bf(x0.y * scale);
    u.s[2] = f2bf(x0.z * scale); u.s[3] = f2bf(x0.w * scale);
    u.s[4] = f2bf(x1.x * scale); u.s[5] = f2bf(x1.y * scale);
    u.s[6] = f2bf(x1.z * scale); u.s[7] = f2bf(x1.w * scale);
    *(int4*)(dst + off) = u.v;
}

// ---------------------------------------------------------------------------
// QKV GEMM: Y[m][n] = sum_k A[m][k] * W[n][k], all-bf16.
// 128x256 tile (A fetched once), BK=32, 8 waves (2M x 4N), 4x4 frags each.
// global_load_lds dwordx4 into linear LDS; XOR chunk-swizzle applied on the
// GLOBAL SOURCE and identically on the ds_read side (rule 21).
// 2-phase double-buffer: STAGE(next) -> ds_read+MFMA(cur) -> barrier.
// ---------------------------------------------------------------------------
__global__ __launch_bounds__(512) void gemm_kernel(
    const unsigned short* __restrict__ A0,
    const unsigned short* __restrict__ A1,
    const unsigned short* __restrict__ A2,
    const unsigned short* __restrict__ W0,
    const unsigned short* __restrict__ W1,
    const unsigned short* __restrict__ W2,
    unsigned short* __restrict__ Y0,
    unsigned short* __restrict__ Y1,
    unsigned short* __restrict__ Y2)
{
    const int z = blockIdx.y;
    const unsigned short* A = (z == 0) ? A0 : (z == 1) ? A1 : A2;
    const unsigned short* W = (z == 0) ? W0 : (z == 1) ? W1 : W2;
    unsigned short* Y       = (z == 0) ? Y0 : (z == 1) ? Y1 : Y2;

    const int bm = blockIdx.x;   // 272 M-tiles

    __shared__ unsigned short As[2][128 * 32];   // 8 KB x2, linear
    __shared__ unsigned short Bs[2][256 * 32];   // 16 KB x2, linear

    const int tid  = threadIdx.x;
    const int wv   = tid >> 6;     // 0..7
    const int lane = tid & 63;
    const int wm   = wv & 1;       // M half (64 rows)
    const int wn   = wv >> 1;      // N quarter (64 cols)
    const int quad = lane >> 4;
    const int l16  = lane & 15;

    // --- staging geometry (source pre-swizzle; LDS dest is HW-linear) ---
    const int s     = lane >> 2;            // sub-row 0..15 within wave's 16
    const int chunk = lane & 3;             // 16B chunk within 64B LDS row
    const int fsw   = (s ^ (s >> 2)) & 3;   // f(row&15)
    const int cg    = chunk ^ fsw;          // global chunk feeding this slot
    const int srow  = wv * 16 + s;          // 0..127
    const unsigned short* gA  = A + (size_t)(bm * 128 + srow) * 256 + cg * 8;
    const unsigned short* gB0 = W + (size_t)srow * 256 + cg * 8;
    const unsigned short* gB1 = W + (size_t)(128 + srow) * 256 + cg * 8;
    unsigned short* lA  = &As[0][wv * 512 + lane * 8];
    unsigned short* lB0 = &Bs[0][wv * 512 + lane * 8];
    unsigned short* lB1 = &Bs[0][4096 + wv * 512 + lane * 8];

    // --- read-side swizzle (same involution) ---
    const int rch8 = (quad ^ ((l16 ^ (l16 >> 2)) & 3)) * 8;

    v4f acc[4][4] = {};

    gld16(gA,  lA);
    gld16(gB0, lB0);
    gld16(gB1, lB1);
    __syncthreads();

    for (int kt = 0; kt < 8; ++kt) {
        const int cur = kt & 1;
        if (kt < 7) {
            const int nk = (kt + 1) * 32;
            const int nb = cur ^ 1;
            gld16(gA  + nk, lA  + nb * 4096);
            gld16(gB0 + nk, lB0 + nb * 8192);
            gld16(gB1 + nk, lB1 + nb * 8192);
        }
        v8s a[4], b[4];
        #pragma unroll
        for (int i = 0; i < 4; ++i)
            a[i] = *(const v8s*)(&As[cur][(wm * 64 + i * 16 + l16) * 32 + rch8]);
        #pragma unroll
        for (int j = 0; j < 4; ++j)
            b[j] = *(const v8s*)(&Bs[cur][(wn * 64 + j * 16 + l16) * 32 + rch8]);
        #pragma unroll
        for (int i = 0; i < 4; ++i)
            #pragma unroll
            for (int j = 0; j < 4; ++j)
                acc[i][j] = __builtin_amdgcn_mfma_f32_16x16x32_bf16(
                    a[i], b[j], acc[i][j], 0, 0, 0);
        __syncthreads();
    }

    #pragma unroll
    for (int i = 0; i < 4; ++i)
        #pragma unroll
        for (int j = 0; j < 4; ++j)
            #pragma unroll
            for (int r = 0; r < 4; ++r) {
                int gm = bm * 128 + wm * 64 + i * 16 + quad * 4 + r;
                int gn = wn * 64 + j * 16 + l16;
                Y[(size_t)gm * 256 + gn] = f2bf(acc[i][j][r]);
            }
}

// ---------------------------------------------------------------------------
// Output GEMM: out[m][n] = sum_k Att[m][k]*Wp[n][k] + bias[n], fp32 store.
// BM=64 -> 544 blocks (vs 272: kills the 53%-util tail), 256 thr (4 waves,
// 1M x 4N), same 2-phase gld16 + source/read swizzle structure.
// ---------------------------------------------------------------------------
__global__ __launch_bounds__(256) void gemmo_kernel(
    const unsigned short* __restrict__ A,
    const unsigned short* __restrict__ W,
    const float* __restrict__ bias,
    float* __restrict__ out)
{
    const int bm = blockIdx.x;   // 544 tiles of 64 rows

    __shared__ unsigned short As[2][64 * 32];    // 4 KB x2
    __shared__ unsigned short Bs[2][256 * 32];   // 16 KB x2

    const int tid  = threadIdx.x;
    const int lane = tid & 63;
    const int wn   = tid >> 6;     // N quarter
    const int quad = lane >> 4;
    const int l16  = lane & 15;

    // staging: slot t -> row=t>>2, chunk=t&3; 1 gld16 for A, 4 for B
    const int arow  = tid >> 2;               // 0..63
    const int chunk = tid & 3;
    const int cgA   = (chunk ^ ((arow ^ (arow >> 2)) & 3)) * 8;
    const unsigned short* gA = A + (size_t)(bm * 64 + arow) * 256 + cgA;
    const unsigned short* gB = W + (size_t)arow * 256 + cgA;   // + p*64 rows
    unsigned short* lA = &As[0][tid * 8];
    unsigned short* lB = &Bs[0][tid * 8];

    const int rch8 = (quad ^ ((l16 ^ (l16 >> 2)) & 3)) * 8;

    v4f acc[4][4] = {};

    gld16(gA, lA);
    #pragma unroll
    for (int p = 0; p < 4; ++p)
        gld16(gB + (size_t)p * 64 * 256, lB + p * 2048);
    __syncthreads();

    for (int kt = 0; kt < 8; ++kt) {
        const int cur = kt & 1;
        if (kt < 7) {
            const int nk = (kt + 1) * 32;
            const int nb = cur ^ 1;
            gld16(gA + nk, lA + nb * 2048);
            #pragma unroll
            for (int p = 0; p < 4; ++p)
                gld16(gB + (size_t)p * 64 * 256 + nk, lB + nb * 8192 + p * 2048);
        }
        v8s a[4], b[4];
        #pragma unroll
        for (int i = 0; i < 4; ++i)
            a[i] = *(const v8s*)(&As[cur][(i * 16 + l16) * 32 + rch8]);
        #pragma unroll
        for (int j = 0; j < 4; ++j)
            b[j] = *(const v8s*)(&Bs[cur][(wn * 64 + j * 16 + l16) * 32 + rch8]);
        #pragma unroll
        for (int i = 0; i < 4; ++i)
            #pragma unroll
            for (int j = 0; j < 4; ++j)
                acc[i][j] = __builtin_amdgcn_mfma_f32_16x16x32_bf16(
                    a[i], b[j], acc[i][j], 0, 0, 0);
        __syncthreads();
    }

    #pragma unroll
    for (int i = 0; i < 4; ++i)
        #pragma unroll
        for (int j = 0; j < 4; ++j)
            #pragma unroll
            for (int r = 0; r < 4; ++r) {
                int gm = bm * 64 + i * 16 + quad * 4 + r;
                int gn = wn * 64 + j * 16 + l16;
                out[(size_t)gm * 256 + gn] = acc[i][j][r] + bias[gn];
            }
}

// ---------------------------------------------------------------------------
// Fused attention. Q pre-scaled into log2 domain (no-max softmax).
// R3: (1) XCD-grouped 1-D grid: the 4 qt-siblings of each (b,j,h) get ids
//     congruent mod 8 -> same XCD L2 -> KV fetched once, not 4x.
// (2) V-scatter write order rotated per lane: kills the uniform 8-way LDS
//     bank conflict (all cd-groups were congruent mod 64 shorts).
// (3) T14 reg-staged K/V prefetch: issue kc+1 loads after the publish
//     barrier, hide HBM latency under the kc compute phase.
// ---------------------------------------------------------------------------
#define VST 136   // Vs stride (16B-aligned rows), XOR-swizzled s-blocks
#define PST 72    // Ps stride: 144B rows, 16B-aligned, 2-way-free

__global__ __launch_bounds__(256, 4) void attn_kernel(
    const unsigned short* __restrict__ Qp,
    const unsigned short* __restrict__ Kp,
    const unsigned short* __restrict__ Vp,
    unsigned short* __restrict__ Att)
{
    // XCD-grouped id mapping: ids {x + 8*qt + 32*k} share bjh = x + 8*k and
    // are congruent mod 8 -> same XCD under round-robin dispatch.
    const int id  = blockIdx.x;            // 0..2175
    const int bjh = (id & 7) | ((id >> 5) << 3);   // 0..543
    const int qt  = (id >> 3) & 3;
    const int h   = bjh & 7;
    const int bj  = bjh >> 3;
    const int j   = bj % 17;
    const int b_  = bj / 17;

    __shared__ unsigned short Ks[128 * 40];    // [s][cd], pad 40   (10.25 KB)
    __shared__ unsigned short Vs[32 * VST];    // [cd][s], swizzled (8.7 KB)
    __shared__ unsigned short Ps[128 * PST];   // [qrow][s-half]    (18.4 KB)
    __shared__ float Ls[128];                  // row sums          (0.5 KB)

    const int tid  = threadIdx.x;
    const int wave = tid >> 6;
    const int lane = tid & 63;
    const int quad = lane >> 4;
    const int l16  = lane & 15;

    const int base0 = b_ * 512 * RST + j * 256 + h * 32;

    // Q fragments straight from global (each wave reads only its own rows)
    v8s qa[2];
    #pragma unroll
    for (int fi = 0; fi < 2; ++fi)
        qa[fi] = *(const v8s*)(
            Qp + base0 + (qt * 128 + wave * 32 + fi * 16 + l16) * RST + quad * 8);

    // staging geometry (constant across kc)
    const int krow0 = wave * 16 + l16;             // K row (+c*64)
    const int vsrow = tid >> 2;                    // V srow (+c*64)
    const int vw    = tid & 3;                     // cd group
    const int vcd0  = vw << 3;

    float lacc[2] = {0.f, 0.f};
    v4f accO[2][2] = {};

    // T14 prologue: load kc=0 into regs
    int4 kreg[2], vreg[2];
    #pragma unroll
    for (int c = 0; c < 2; ++c) {
        kreg[c] = *(const int4*)(Kp + base0 + (krow0 + c * 64) * RST + quad * 8);
        vreg[c] = *(const int4*)(Vp + base0 + (vsrow + c * 64) * RST + vcd0);
    }

    for (int kc = 0; kc < 4; ++kc) {
        // write staged regs -> LDS (prev readers done: trailing barrier)
        #pragma unroll
        for (int c = 0; c < 2; ++c)
            *(int4*)(&Ks[(krow0 + c * 64) * 40 + quad * 8]) = kreg[c];
        #pragma unroll
        for (int c = 0; c < 2; ++c) {
            int srow = vsrow + c * 64;
            int xof  = (((srow >> 3) ^ vw) << 3) + (srow & 7);
            union { int4 v; unsigned short s[8]; } u;
            u.v = vreg[c];
            #pragma unroll
            for (int i = 0; i < 8; ++i) {
                int m = (i + 2 * vw) & 7;   // rotated order: disjoint banks
                Vs[(vcd0 + m) * VST + xof] = u.s[m];
            }
        }
        __syncthreads();   // publish kc

        if (kc < 3) {      // issue kc+1 loads; land during compute below
            const int nko = (kc + 1) * 128 * RST;
            #pragma unroll
            for (int c = 0; c < 2; ++c) {
                kreg[c] = *(const int4*)(Kp + base0 + nko + (krow0 + c * 64) * RST + quad * 8);
                vreg[c] = *(const int4*)(Vp + base0 + nko + (vsrow + c * 64) * RST + vcd0);
            }
        }

        #pragma unroll
        for (int half = 0; half < 2; ++half) {
            // S^T = K @ Q^T; C-layout col=qrow(l16), row=s
            v4f accST[4][2] = {};
            __builtin_amdgcn_s_setprio(1);
            #pragma unroll
            for (int si = 0; si < 4; ++si) {
                v8s kb = *(const v8s*)(&Ks[((half * 4 + si) * 16 + l16) * 40 + quad * 8]);
                #pragma unroll
                for (int fi = 0; fi < 2; ++fi)
                    accST[si][fi] = __builtin_amdgcn_mfma_f32_16x16x32_bf16(
                        kb, qa[fi], accST[si][fi], 0, 0, 0);
            }
            __builtin_amdgcn_s_setprio(0);
            // exp2 (no max-sub), packed b64 P writes, lane-local l accum
            #pragma unroll
            for (int fi = 0; fi < 2; ++fi) {
                int prow = (wave * 32 + fi * 16 + l16) * PST;
                #pragma unroll
                for (int si = 0; si < 4; ++si) {
                    float p0 = fexp2(accST[si][fi][0]);
                    float p1 = fexp2(accST[si][fi][1]);
                    float p2 = fexp2(accST[si][fi][2]);
                    float p3 = fexp2(accST[si][fi][3]);
                    lacc[fi] += (p0 + p1) + (p2 + p3);
                    uint2 pk;
                    pk.x = pkbf(p0, p1);
                    pk.y = pkbf(p2, p3);
                    *(uint2*)(&Ps[prow + si * 16 + quad * 4]) = pk;
                }
            }
            // Ps rows wave-private: drain LDS writes only
            asm volatile("s_waitcnt lgkmcnt(0)" ::: "memory");

            // O += P @ V over this half (ks local 0..1)
            __builtin_amdgcn_s_setprio(1);
            #pragma unroll
            for (int ks = 0; ks < 2; ++ks) {
                v8s pa[2];
                #pragma unroll
                for (int fi = 0; fi < 2; ++fi)
                    pa[fi] = *(const v8s*)(&Ps[(wave * 32 + fi * 16 + l16) * PST +
                                               ks * 32 + quad * 8]);
                #pragma unroll
                for (int nj = 0; nj < 2; ++nj) {
                    int cd  = nj * 16 + l16;
                    int blk = (half * 8 + ks * 4 + quad) ^ (cd >> 3);
                    v8s vb = *(const v8s*)(&Vs[cd * VST + (blk << 3)]);
                    #pragma unroll
                    for (int fi = 0; fi < 2; ++fi)
                        accO[fi][nj] = __builtin_amdgcn_mfma_f32_16x16x32_bf16(
                            pa[fi], vb, accO[fi][nj], 0, 0, 0);
                }
            }
            __builtin_amdgcn_s_setprio(0);
        }
        __syncthreads();   // all reads of Ks/Vs done before next overwrite
    }

    // final l: reduce lane partials across the 4 quads sharing each qrow
    #pragma unroll
    for (int fi = 0; fi < 2; ++fi) {
        float lv = lacc[fi];
        lv += __shfl_xor(lv, 16);
        lv += __shfl_xor(lv, 32);
        if (quad == 0) Ls[wave * 32 + fi * 16 + l16] = lv;
    }
    asm volatile("s_waitcnt lgkmcnt(0)" ::: "memory");

    // epilogue: Att row-major [(b,t,j)][(h,cd)]
    #pragma unroll
    for (int fi = 0; fi < 2; ++fi) {
        float4 lv = *(float4*)(&Ls[wave * 32 + fi * 16 + quad * 4]);
        float rl[4] = {1.f / lv.x, 1.f / lv.y, 1.f / lv.z, 1.f / lv.w};
        #pragma unroll
        for (int nj = 0; nj < 2; ++nj) {
            #pragma unroll
            for (int r = 0; r < 4; ++r) {
                int trow = qt * 128 + wave * 32 + fi * 16 + quad * 4 + r;
                int cd   = nj * 16 + l16;
                float v  = accO[fi][nj][r] * rl[r];
                Att[(size_t)(base0 + trow * RST + cd)] = f2bf(v);
            }
        }
    }
}

extern "C" void kernel_launch(void* const* d_in, const int* in_sizes, int n_in,
                              void* d_out, int out_size, void* d_ws, size_t ws_size,
                              hipStream_t stream) {
    const float* q  = (const float*)d_in[0];
    const float* kv = (const float*)d_in[1];
    const float* Wq = (const float*)d_in[2];
    const float* Wk = (const float*)d_in[3];
    const float* Wv = (const float*)d_in[4];
    const float* Wp = (const float*)d_in[5];
    const float* bp = (const float*)d_in[6];

    unsigned short* ws  = (unsigned short*)d_ws;
    unsigned short* Qp  = ws;                 // SZE
    unsigned short* Kp  = ws + SZE;           // SZE
    unsigned short* Vp  = ws + 2 * SZE;       // SZE
    unsigned short* qb  = ws + 3 * SZE;       // SZE (aliased by Att later)
    unsigned short* kvb = ws + 4 * SZE;       // SZE
    unsigned short* Wqb = ws + 5 * SZE;
    unsigned short* Wkb = Wqb + WSZ;
    unsigned short* Wvb = Wkb + WSZ;
    unsigned short* Wpb = Wvb + WSZ;
    unsigned short* Att = qb;                 // qb dead after QKV gemm
    float* out = (float*)d_out;

    // 0) fp32 -> bf16 prep (q scaled by QSCALE)
    prep_kernel<<<8832, 256, 0, stream>>>(q, kv, Wq, Wk, Wv, Wp,
                                          qb, kvb, Wqb, Wkb, Wvb, Wpb);
    // 1) Q/K/V projections (all-bf16), full-N tiles: A fetched once per z
    gemm_kernel<<<dim3(272, 3), 512, 0, stream>>>(
        qb, kvb, kvb, Wqb, Wkb, Wvb, Qp, Kp, Vp);
    // 2) fused attention (XCD-grouped flat grid)
    attn_kernel<<<dim3(2176), 256, 0, stream>>>(Qp, Kp, Vp, Att);
    // 3) output projection + bias (fp32 out), BM=64 tail-friendly grid
    gemmo_kernel<<<dim3(544), 256, 0, stream>>>(Att, Wpb, bp, out);
}

// Round 6
// 210.097 us; speedup vs baseline: 1.2063x; 1.2063x over previous
//
#include <hip/hip_runtime.h>
#include <hip/hip_bf16.h>

// Problem constants
#define BB 4
#define TT 512
#define JJ 17
#define DD 256
#define HH 8
#define MROWS (BB*TT*JJ)            // 34816 = 272 * 128
#define SZE ((size_t)MROWS * DD)    // 8,912,896 elems
#define WSZ (DD*DD)                 // 65536
#define QSCALE 0.2550265247510319f  // 32^-0.5 * log2(e)
#define RST (17*256)                // row stride of [*, j, d] tensors (4352)

typedef short v8s __attribute__((ext_vector_type(8)));   // 8 bf16 in 4 VGPRs
typedef float v4f __attribute__((ext_vector_type(4)));   // MFMA accumulator

// f32->bf16 round-to-nearest-even (accuracy-critical paths)
__device__ __forceinline__ unsigned short f2bf(float f) {
    union { float f; unsigned int u; } c; c.f = f;
    unsigned int u = c.u;
    return (unsigned short)((u + 0x7FFF + ((u >> 16) & 1)) >> 16);
}
// hot path: pack two f32 -> two bf16 (round-half-up), 2 add + 1 perm
__device__ __forceinline__ unsigned int pkbf(float lo, float hi) {
    union { float f; unsigned int u; } a, b; a.f = lo; b.f = hi;
    return __builtin_amdgcn_perm(b.u + 0x8000u, a.u + 0x8000u, 0x07060302u);
}
// bare v_exp_f32 (2^x); scores bounded, denorm P irrelevant to softmax sum.
__device__ __forceinline__ float fexp2(float x) {
    return __builtin_amdgcn_exp2f(x);
}

// async global->LDS, 16B per lane (HW: wave-uniform base + lane*16)
__device__ __forceinline__ void gld16(const unsigned short* g, unsigned short* l) {
    __builtin_amdgcn_global_load_lds(
        (const __attribute__((address_space(1))) void*)g,
        (__attribute__((address_space(3))) void*)l,
        16, 0, 0);
}

// ---------------------------------------------------------------------------
// Prep: fp32 -> bf16 (RNE). q gets QSCALE folded in (linearity of the proj).
// 8 elems/thread, exact grid cover.
// ---------------------------------------------------------------------------
__global__ __launch_bounds__(256) void prep_kernel(
    const float* __restrict__ q, const float* __restrict__ kv,
    const float* __restrict__ Wq, const float* __restrict__ Wk,
    const float* __restrict__ Wv, const float* __restrict__ Wp,
    unsigned short* __restrict__ qb, unsigned short* __restrict__ kvb,
    unsigned short* __restrict__ Wqb, unsigned short* __restrict__ Wkb,
    unsigned short* __restrict__ Wvb, unsigned short* __restrict__ Wpb)
{
    size_t i = ((size_t)blockIdx.x * 256 + threadIdx.x) * 8;
    const float* src; unsigned short* dst; size_t off; float scale = 1.f;
    if (i < SZE)            { src = q;  dst = qb;  off = i;        scale = QSCALE; }
    else if (i < 2 * SZE)   { src = kv; dst = kvb; off = i - SZE; }
    else {
        size_t k = i - 2 * SZE;
        int w = (int)(k >> 16);         // WSZ = 65536
        off = k & (WSZ - 1);
        src = (w == 0) ? Wq : (w == 1) ? Wk : (w == 2) ? Wv : Wp;
        dst = (w == 0) ? Wqb : (w == 1) ? Wkb : (w == 2) ? Wvb : Wpb;
    }
    float4 x0 = *(const float4*)(src + off);
    float4 x1 = *(const float4*)(src + off + 4);
    union { unsigned short s[8]; int4 v; } u;
    u.s[0] = f2bf(x0.x * scale); u.s[1] = f2bf(x0.y * scale);
    u.s[2] = f2bf(x0.z * scale); u.s[3] = f2bf(x0.w * scale);
    u.s[4] = f2bf(x1.x * scale); u.s[5] = f2bf(x1.y * scale);
    u.s[6] = f2bf(x1.z * scale); u.s[7] = f2bf(x1.w * scale);
    *(int4*)(dst + off) = u.v;
}

// ---------------------------------------------------------------------------
// QKV GEMM: Y[m][n] = sum_k A[m][k] * W[n][k], all-bf16.
// 128x256 tile (A fetched once), BK=32, 8 waves (2M x 4N), 4x4 frags each.
// global_load_lds dwordx4 into linear LDS; XOR chunk-swizzle applied on the
// GLOBAL SOURCE and identically on the ds_read side (rule 21).
// 2-phase double-buffer: STAGE(next) -> ds_read+MFMA(cur) -> barrier.
// ---------------------------------------------------------------------------
__global__ __launch_bounds__(512) void gemm_kernel(
    const unsigned short* __restrict__ A0,
    const unsigned short* __restrict__ A1,
    const unsigned short* __restrict__ A2,
    const unsigned short* __restrict__ W0,
    const unsigned short* __restrict__ W1,
    const unsigned short* __restrict__ W2,
    unsigned short* __restrict__ Y0,
    unsigned short* __restrict__ Y1,
    unsigned short* __restrict__ Y2)
{
    const int z = blockIdx.y;
    const unsigned short* A = (z == 0) ? A0 : (z == 1) ? A1 : A2;
    const unsigned short* W = (z == 0) ? W0 : (z == 1) ? W1 : W2;
    unsigned short* Y       = (z == 0) ? Y0 : (z == 1) ? Y1 : Y2;

    const int bm = blockIdx.x;   // 272 M-tiles

    __shared__ unsigned short As[2][128 * 32];   // 8 KB x2, linear
    __shared__ unsigned short Bs[2][256 * 32];   // 16 KB x2, linear

    const int tid  = threadIdx.x;
    const int wv   = tid >> 6;     // 0..7
    const int lane = tid & 63;
    const int wm   = wv & 1;       // M half (64 rows)
    const int wn   = wv >> 1;      // N quarter (64 cols)
    const int quad = lane >> 4;
    const int l16  = lane & 15;

    // --- staging geometry (source pre-swizzle; LDS dest is HW-linear) ---
    const int s     = lane >> 2;            // sub-row 0..15 within wave's 16
    const int chunk = lane & 3;             // 16B chunk within 64B LDS row
    const int fsw   = (s ^ (s >> 2)) & 3;   // f(row&15)
    const int cg    = chunk ^ fsw;          // global chunk feeding this slot
    const int srow  = wv * 16 + s;          // 0..127
    const unsigned short* gA  = A + (size_t)(bm * 128 + srow) * 256 + cg * 8;
    const unsigned short* gB0 = W + (size_t)srow * 256 + cg * 8;
    const unsigned short* gB1 = W + (size_t)(128 + srow) * 256 + cg * 8;
    unsigned short* lA  = &As[0][wv * 512 + lane * 8];
    unsigned short* lB0 = &Bs[0][wv * 512 + lane * 8];
    unsigned short* lB1 = &Bs[0][4096 + wv * 512 + lane * 8];

    // --- read-side swizzle (same involution) ---
    const int rch8 = (quad ^ ((l16 ^ (l16 >> 2)) & 3)) * 8;

    v4f acc[4][4] = {};

    gld16(gA,  lA);
    gld16(gB0, lB0);
    gld16(gB1, lB1);
    __syncthreads();

    for (int kt = 0; kt < 8; ++kt) {
        const int cur = kt & 1;
        if (kt < 7) {
            const int nk = (kt + 1) * 32;
            const int nb = cur ^ 1;
            gld16(gA  + nk, lA  + nb * 4096);
            gld16(gB0 + nk, lB0 + nb * 8192);
            gld16(gB1 + nk, lB1 + nb * 8192);
        }
        v8s a[4], b[4];
        #pragma unroll
        for (int i = 0; i < 4; ++i)
            a[i] = *(const v8s*)(&As[cur][(wm * 64 + i * 16 + l16) * 32 + rch8]);
        #pragma unroll
        for (int j = 0; j < 4; ++j)
            b[j] = *(const v8s*)(&Bs[cur][(wn * 64 + j * 16 + l16) * 32 + rch8]);
        #pragma unroll
        for (int i = 0; i < 4; ++i)
            #pragma unroll
            for (int j = 0; j < 4; ++j)
                acc[i][j] = __builtin_amdgcn_mfma_f32_16x16x32_bf16(
                    a[i], b[j], acc[i][j], 0, 0, 0);
        __syncthreads();
    }

    #pragma unroll
    for (int i = 0; i < 4; ++i)
        #pragma unroll
        for (int j = 0; j < 4; ++j)
            #pragma unroll
            for (int r = 0; r < 4; ++r) {
                int gm = bm * 128 + wm * 64 + i * 16 + quad * 4 + r;
                int gn = wn * 64 + j * 16 + l16;
                Y[(size_t)gm * 256 + gn] = f2bf(acc[i][j][r]);
            }
}

// ---------------------------------------------------------------------------
// Output GEMM: out[m][n] = sum_k Att[m][k]*Wp[n][k] + bias[n], fp32 store.
// BM=64 -> 544 blocks (kills the 53%-util tail), 256 thr (1M x 4N),
// same 2-phase gld16 + source/read swizzle structure.
// ---------------------------------------------------------------------------
__global__ __launch_bounds__(256) void gemmo_kernel(
    const unsigned short* __restrict__ A,
    const unsigned short* __restrict__ W,
    const float* __restrict__ bias,
    float* __restrict__ out)
{
    const int bm = blockIdx.x;   // 544 tiles of 64 rows

    __shared__ unsigned short As[2][64 * 32];    // 4 KB x2
    __shared__ unsigned short Bs[2][256 * 32];   // 16 KB x2

    const int tid  = threadIdx.x;
    const int lane = tid & 63;
    const int wn   = tid >> 6;     // N quarter
    const int quad = lane >> 4;
    const int l16  = lane & 15;

    // staging: slot t -> row=t>>2, chunk=t&3; 1 gld16 for A, 4 for B
    const int arow  = tid >> 2;               // 0..63
    const int chunk = tid & 3;
    const int cgA   = (chunk ^ ((arow ^ (arow >> 2)) & 3)) * 8;
    const unsigned short* gA = A + (size_t)(bm * 64 + arow) * 256 + cgA;
    const unsigned short* gB = W + (size_t)arow * 256 + cgA;   // + p*64 rows
    unsigned short* lA = &As[0][tid * 8];
    unsigned short* lB = &Bs[0][tid * 8];

    const int rch8 = (quad ^ ((l16 ^ (l16 >> 2)) & 3)) * 8;

    v4f acc[4][4] = {};

    gld16(gA, lA);
    #pragma unroll
    for (int p = 0; p < 4; ++p)
        gld16(gB + (size_t)p * 64 * 256, lB + p * 2048);
    __syncthreads();

    for (int kt = 0; kt < 8; ++kt) {
        const int cur = kt & 1;
        if (kt < 7) {
            const int nk = (kt + 1) * 32;
            const int nb = cur ^ 1;
            gld16(gA + nk, lA + nb * 2048);
            #pragma unroll
            for (int p = 0; p < 4; ++p)
                gld16(gB + (size_t)p * 64 * 256 + nk, lB + nb * 8192 + p * 2048);
        }
        v8s a[4], b[4];
        #pragma unroll
        for (int i = 0; i < 4; ++i)
            a[i] = *(const v8s*)(&As[cur][(i * 16 + l16) * 32 + rch8]);
        #pragma unroll
        for (int j = 0; j < 4; ++j)
            b[j] = *(const v8s*)(&Bs[cur][(wn * 64 + j * 16 + l16) * 32 + rch8]);
        #pragma unroll
        for (int i = 0; i < 4; ++i)
            #pragma unroll
            for (int j = 0; j < 4; ++j)
                acc[i][j] = __builtin_amdgcn_mfma_f32_16x16x32_bf16(
                    a[i], b[j], acc[i][j], 0, 0, 0);
        __syncthreads();
    }

    #pragma unroll
    for (int i = 0; i < 4; ++i)
        #pragma unroll
        for (int j = 0; j < 4; ++j)
            #pragma unroll
            for (int r = 0; r < 4; ++r) {
                int gm = bm * 64 + i * 16 + quad * 4 + r;
                int gn = wn * 64 + j * 16 + l16;
                out[(size_t)gm * 256 + gn] = acc[i][j][r] + bias[gn];
            }
}

// ---------------------------------------------------------------------------
// Fused attention — EXACT R2 body (fully-passing run: 56.5us, absmax
// 0.00684 through all tripwires): direct global->LDS staging between double
// barriers, static V scatter from fresh loads, asm-lgkmcnt Ps/Ls fences,
// fexp2, setprio. Only change vs R2: XCD-grouped flat grid (pure index
// bijection, proven in passing R3; -68MB FETCH). T14 reg-staged prefetch is
// QUARANTINED: both runs containing it (R4/R5) failed determinism checks.
// ---------------------------------------------------------------------------
#define VST 136   // Vs stride (16B-aligned rows), XOR-swizzled s-blocks
#define PST 72    // Ps stride: 144B rows, 16B-aligned, 2-way-free

__global__ __launch_bounds__(256) void attn_kernel(
    const unsigned short* __restrict__ Qp,
    const unsigned short* __restrict__ Kp,
    const unsigned short* __restrict__ Vp,
    unsigned short* __restrict__ Att)
{
    // XCD-grouped id mapping: ids {x + 8*qt + 32*k} share bjh = x + 8*k and
    // are congruent mod 8 -> same XCD under round-robin dispatch.
    const int id  = blockIdx.x;            // 0..2175
    const int bjh = (id & 7) | ((id >> 5) << 3);   // 0..543
    const int qt  = (id >> 3) & 3;
    const int h   = bjh & 7;
    const int bj  = bjh >> 3;
    const int j   = bj % 17;
    const int b_  = bj / 17;

    __shared__ unsigned short Ks[128 * 40];    // [s][cd], pad 40   (10.25 KB)
    __shared__ unsigned short Vs[32 * VST];    // [cd][s], swizzled (8.7 KB)
    __shared__ unsigned short Ps[128 * PST];   // [qrow][s-half]    (18.4 KB)
    __shared__ float Ls[128];                  // row sums          (0.5 KB)

    const int tid  = threadIdx.x;
    const int wave = tid >> 6;
    const int lane = tid & 63;
    const int quad = lane >> 4;
    const int l16  = lane & 15;

    const int base0 = b_ * 512 * RST + j * 256 + h * 32;

    // Q fragments straight from global (each wave reads only its own rows)
    v8s qa[2];
    #pragma unroll
    for (int fi = 0; fi < 2; ++fi)
        qa[fi] = *(const v8s*)(
            Qp + base0 + (qt * 128 + wave * 32 + fi * 16 + l16) * RST + quad * 8);

    float lacc[2] = {0.f, 0.f};
    v4f accO[2][2] = {};

    for (int kc = 0; kc < 4; ++kc) {
        __syncthreads();   // protect previous-iteration Ks/Vs reads
        // stage K chunk [128][32], conflict-free writer mapping
        #pragma unroll
        for (int c = 0; c < 2; ++c) {
            int krow = wave * 16 + l16 + c * 64;
            *(int4*)(&Ks[krow * 40 + quad * 8]) = *(const int4*)(
                Kp + base0 + (kc * 128 + krow) * RST + quad * 8);
        }
        // stage V chunk transposed with XOR swizzle:
        // (cd, srow) -> Vs[cd*VST + ((sblk ^ (cd>>3))<<3) + (srow&7)]
        #pragma unroll
        for (int c = 0; c < 2; ++c) {
            int idx  = c * 256 + tid;
            int srow = idx >> 2;
            int cd0  = (idx & 3) << 3;
            int xof  = (((srow >> 3) ^ (cd0 >> 3)) << 3) + (srow & 7);
            union { int4 v; unsigned short s[8]; } u;
            u.v = *(const int4*)(
                Vp + base0 + (kc * 128 + srow) * RST + cd0);
            #pragma unroll
            for (int i = 0; i < 8; ++i)
                Vs[(cd0 + i) * VST + xof] = u.s[i];
        }
        __syncthreads();

        #pragma unroll
        for (int half = 0; half < 2; ++half) {
            // S^T = K @ Q^T; C-layout col=qrow(l16), row=s
            v4f accST[4][2] = {};
            __builtin_amdgcn_s_setprio(1);
            #pragma unroll
            for (int si = 0; si < 4; ++si) {
                v8s kb = *(const v8s*)(&Ks[((half * 4 + si) * 16 + l16) * 40 + quad * 8]);
                #pragma unroll
                for (int fi = 0; fi < 2; ++fi)
                    accST[si][fi] = __builtin_amdgcn_mfma_f32_16x16x32_bf16(
                        kb, qa[fi], accST[si][fi], 0, 0, 0);
            }
            __builtin_amdgcn_s_setprio(0);
            // exp2 (no max-sub), packed b64 P writes, lane-local l accum
            #pragma unroll
            for (int fi = 0; fi < 2; ++fi) {
                int prow = (wave * 32 + fi * 16 + l16) * PST;
                #pragma unroll
                for (int si = 0; si < 4; ++si) {
                    float p0 = fexp2(accST[si][fi][0]);
                    float p1 = fexp2(accST[si][fi][1]);
                    float p2 = fexp2(accST[si][fi][2]);
                    float p3 = fexp2(accST[si][fi][3]);
                    lacc[fi] += (p0 + p1) + (p2 + p3);
                    uint2 pk;
                    pk.x = pkbf(p0, p1);
                    pk.y = pkbf(p2, p3);
                    *(uint2*)(&Ps[prow + si * 16 + quad * 4]) = pk;
                }
            }
            // Ps rows wave-private: drain LDS writes only
            asm volatile("s_waitcnt lgkmcnt(0)" ::: "memory");

            // O += P @ V over this half (ks local 0..1)
            __builtin_amdgcn_s_setprio(1);
            #pragma unroll
            for (int ks = 0; ks < 2; ++ks) {
                v8s pa[2];
                #pragma unroll
                for (int fi = 0; fi < 2; ++fi)
                    pa[fi] = *(const v8s*)(&Ps[(wave * 32 + fi * 16 + l16) * PST +
                                               ks * 32 + quad * 8]);
                #pragma unroll
                for (int nj = 0; nj < 2; ++nj) {
                    int cd  = nj * 16 + l16;
                    int blk = (half * 8 + ks * 4 + quad) ^ (cd >> 3);
                    v8s vb = *(const v8s*)(&Vs[cd * VST + (blk << 3)]);
                    #pragma unroll
                    for (int fi = 0; fi < 2; ++fi)
                        accO[fi][nj] = __builtin_amdgcn_mfma_f32_16x16x32_bf16(
                            pa[fi], vb, accO[fi][nj], 0, 0, 0);
                }
            }
            __builtin_amdgcn_s_setprio(0);
        }
    }

    // final l: reduce lane partials across the 4 quads sharing each qrow
    #pragma unroll
    for (int fi = 0; fi < 2; ++fi) {
        float lv = lacc[fi];
        lv += __shfl_xor(lv, 16);
        lv += __shfl_xor(lv, 32);
        if (quad == 0) Ls[wave * 32 + fi * 16 + l16] = lv;
    }
    asm volatile("s_waitcnt lgkmcnt(0)" ::: "memory");

    // epilogue: Att row-major [(b,t,j)][(h,cd)]
    #pragma unroll
    for (int fi = 0; fi < 2; ++fi) {
        float4 lv = *(float4*)(&Ls[wave * 32 + fi * 16 + quad * 4]);
        float rl[4] = {1.f / lv.x, 1.f / lv.y, 1.f / lv.z, 1.f / lv.w};
        #pragma unroll
        for (int nj = 0; nj < 2; ++nj) {
            #pragma unroll
            for (int r = 0; r < 4; ++r) {
                int trow = qt * 128 + wave * 32 + fi * 16 + quad * 4 + r;
                int cd   = nj * 16 + l16;
                float v  = accO[fi][nj][r] * rl[r];
                Att[(size_t)(base0 + trow * RST + cd)] = f2bf(v);
            }
        }
    }
}

extern "C" void kernel_launch(void* const* d_in, const int* in_sizes, int n_in,
                              void* d_out, int out_size, void* d_ws, size_t ws_size,
                              hipStream_t stream) {
    const float* q  = (const float*)d_in[0];
    const float* kv = (const float*)d_in[1];
    const float* Wq = (const float*)d_in[2];
    const float* Wk = (const float*)d_in[3];
    const float* Wv = (const float*)d_in[4];
    const float* Wp = (const float*)d_in[5];
    const float* bp = (const float*)d_in[6];

    unsigned short* ws  = (unsigned short*)d_ws;
    unsigned short* Qp  = ws;                 // SZE
    unsigned short* Kp  = ws + SZE;           // SZE
    unsigned short* Vp  = ws + 2 * SZE;       // SZE
    unsigned short* qb  = ws + 3 * SZE;       // SZE (aliased by Att later)
    unsigned short* kvb = ws + 4 * SZE;       // SZE
    unsigned short* Wqb = ws + 5 * SZE;
    unsigned short* Wkb = Wqb + WSZ;
    unsigned short* Wvb = Wkb + WSZ;
    unsigned short* Wpb = Wvb + WSZ;
    unsigned short* Att = qb;                 // qb dead after QKV gemm
    float* out = (float*)d_out;

    // 0) fp32 -> bf16 prep (q scaled by QSCALE)
    prep_kernel<<<8832, 256, 0, stream>>>(q, kv, Wq, Wk, Wv, Wp,
                                          qb, kvb, Wqb, Wkb, Wvb, Wpb);
    // 1) Q/K/V projections (all-bf16), full-N tiles: A fetched once per z
    gemm_kernel<<<dim3(272, 3), 512, 0, stream>>>(
        qb, kvb, kvb, Wqb, Wkb, Wvb, Qp, Kp, Vp);
    // 2) fused attention (XCD-grouped flat grid)
    attn_kernel<<<dim3(2176), 256, 0, stream>>>(Qp, Kp, Vp, Att);
    // 3) output projection + bias (fp32 out), BM=64 tail-friendly grid
    gemmo_kernel<<<dim3(544), 256, 0, stream>>>(Att, Wpb, bp, out);
}

// Round 7
// 201.977 us; speedup vs baseline: 1.2548x; 1.0402x over previous
//
#include <hip/hip_runtime.h>
#include <hip/hip_bf16.h>

// Problem constants
#define BB 4
#define TT 512
#define JJ 17
#define DD 256
#define HH 8
#define MROWS (BB*TT*JJ)            // 34816 = 272 * 128
#define SZE ((size_t)MROWS * DD)    // 8,912,896 elems
#define WSZ (DD*DD)                 // 65536
#define QSCALE 0.2550265247510319f  // 32^-0.5 * log2(e)
#define RST (17*256)                // row stride of [*, j, d] tensors (4352)

typedef short v8s __attribute__((ext_vector_type(8)));   // 8 bf16 in 4 VGPRs
typedef float v4f __attribute__((ext_vector_type(4)));   // MFMA accumulator

// f32->bf16 round-to-nearest-even (accuracy-critical paths)
__device__ __forceinline__ unsigned short f2bf(float f) {
    union { float f; unsigned int u; } c; c.f = f;
    unsigned int u = c.u;
    return (unsigned short)((u + 0x7FFF + ((u >> 16) & 1)) >> 16);
}
// hot path: pack two f32 -> two bf16 (round-half-up), 2 add + 1 perm
__device__ __forceinline__ unsigned int pkbf(float lo, float hi) {
    union { float f; unsigned int u; } a, b; a.f = lo; b.f = hi;
    return __builtin_amdgcn_perm(b.u + 0x8000u, a.u + 0x8000u, 0x07060302u);
}
// bare v_exp_f32 (2^x); scores bounded, denorm P irrelevant to softmax sum.
__device__ __forceinline__ float fexp2(float x) {
    return __builtin_amdgcn_exp2f(x);
}

// async global->LDS, 16B per lane (HW: wave-uniform base + lane*16)
__device__ __forceinline__ void gld16(const unsigned short* g, unsigned short* l) {
    __builtin_amdgcn_global_load_lds(
        (const __attribute__((address_space(1))) void*)g,
        (__attribute__((address_space(3))) void*)l,
        16, 0, 0);
}

// ---------------------------------------------------------------------------
// Weights-only prep: fp32 -> bf16 (RNE). q/kv conversion is now fused into
// the QKV GEMM A-staging (saves ~107 MB of qb/kvb round-trip traffic and an
// 8832-block launch). 262144 elems / (256 thr x 8) = 128 blocks, exact.
// ---------------------------------------------------------------------------
__global__ __launch_bounds__(256) void prepw_kernel(
    const float* __restrict__ Wq, const float* __restrict__ Wk,
    const float* __restrict__ Wv, const float* __restrict__ Wp,
    unsigned short* __restrict__ Wqb, unsigned short* __restrict__ Wkb,
    unsigned short* __restrict__ Wvb, unsigned short* __restrict__ Wpb)
{
    size_t k = ((size_t)blockIdx.x * 256 + threadIdx.x) * 8;   // < 262144
    int w = (int)(k >> 16);         // WSZ = 65536
    size_t off = k & (WSZ - 1);
    const float* src = (w == 0) ? Wq : (w == 1) ? Wk : (w == 2) ? Wv : Wp;
    unsigned short* dst = (w == 0) ? Wqb : (w == 1) ? Wkb : (w == 2) ? Wvb : Wpb;
    float4 x0 = *(const float4*)(src + off);
    float4 x1 = *(const float4*)(src + off + 4);
    union { unsigned short s[8]; int4 v; } u;
    u.s[0] = f2bf(x0.x); u.s[1] = f2bf(x0.y);
    u.s[2] = f2bf(x0.z); u.s[3] = f2bf(x0.w);
    u.s[4] = f2bf(x1.x); u.s[5] = f2bf(x1.y);
    u.s[6] = f2bf(x1.z); u.s[7] = f2bf(x1.w);
    *(int4*)(dst + off) = u.v;
}

// ---------------------------------------------------------------------------
// QKV GEMM with fused fp32->bf16 A-conversion:
// Y[m][n] = sum_k f2bf(A32[m][k]*ascale) * W[n][k].
// A (q or kv) is read fp32 and converted during reg-staged LDS writes
// (QSCALE folded for z==0 -> numerics identical to the old prep+gemm).
// 128x256 tile, BK=32, 8 waves (2M x 4N), 4x4 frags of 16x16x32.
// A-staging: float4 x2 load (source XOR-swizzled) -> f2bf x8 -> one
// ds_write_b128 into linear LDS; B-staging: gld16 from bf16 weights.
// Loads issue before the MFMA phase, cvt+write after it -- all within the
// same kt body (no register crosses a barrier; distinct from the
// quarantined attn T14 pattern). Read-side swizzle unchanged (rule 21).
// 2-phase double-buffer, one barrier per K-step.
// ---------------------------------------------------------------------------
__global__ __launch_bounds__(512) void gemm_kernel(
    const float* __restrict__ Aq,    // q fp32   (z==0)
    const float* __restrict__ Akv,   // kv fp32  (z==1,2)
    const unsigned short* __restrict__ W0,
    const unsigned short* __restrict__ W1,
    const unsigned short* __restrict__ W2,
    unsigned short* __restrict__ Y0,
    unsigned short* __restrict__ Y1,
    unsigned short* __restrict__ Y2)
{
    const int z = blockIdx.y;
    const float* A          = (z == 0) ? Aq : Akv;
    const float ascale      = (z == 0) ? QSCALE : 1.f;
    const unsigned short* W = (z == 0) ? W0 : (z == 1) ? W1 : W2;
    unsigned short* Y       = (z == 0) ? Y0 : (z == 1) ? Y1 : Y2;

    const int bm = blockIdx.x;   // 272 M-tiles

    __shared__ unsigned short As[2][128 * 32];   // 8 KB x2, linear
    __shared__ unsigned short Bs[2][256 * 32];   // 16 KB x2, linear

    const int tid  = threadIdx.x;
    const int wv   = tid >> 6;     // 0..7
    const int lane = tid & 63;
    const int wm   = wv & 1;       // M half (64 rows)
    const int wn   = wv >> 1;      // N quarter (64 cols)
    const int quad = lane >> 4;
    const int l16  = lane & 15;

    // --- staging geometry (source pre-swizzle; LDS dest linear) ---
    const int srow  = tid >> 2;             // 0..127
    const int chunk = tid & 3;              // 16B chunk within 64B LDS row
    const int s4    = srow & 15;
    const int cg    = chunk ^ ((s4 ^ (s4 >> 2)) & 3);   // swizzled src chunk
    const float* gA = A + (size_t)(bm * 128 + srow) * 256 + cg * 8;  // fp32!
    const unsigned short* gB0 = W + (size_t)srow * 256 + cg * 8;
    const unsigned short* gB1 = W + (size_t)(128 + srow) * 256 + cg * 8;
    unsigned short* lA  = &As[0][tid * 8];         // == srow*32 + chunk*8
    unsigned short* lB0 = &Bs[0][tid * 8];
    unsigned short* lB1 = &Bs[0][4096 + tid * 8];

    // --- read-side swizzle (same involution; row&15 == l16) ---
    const int rch8 = (quad ^ ((l16 ^ (l16 >> 2)) & 3)) * 8;

    v4f acc[4][4] = {};

    // prologue: stage tile 0
    {
        float4 a0 = *(const float4*)(gA);
        float4 a1 = *(const float4*)(gA + 4);
        union { unsigned short s[8]; int4 v; } ua;
        ua.s[0] = f2bf(a0.x * ascale); ua.s[1] = f2bf(a0.y * ascale);
        ua.s[2] = f2bf(a0.z * ascale); ua.s[3] = f2bf(a0.w * ascale);
        ua.s[4] = f2bf(a1.x * ascale); ua.s[5] = f2bf(a1.y * ascale);
        ua.s[6] = f2bf(a1.z * ascale); ua.s[7] = f2bf(a1.w * ascale);
        *(int4*)(lA) = ua.v;
    }
    gld16(gB0, lB0);
    gld16(gB1, lB1);
    __syncthreads();

    for (int kt = 0; kt < 8; ++kt) {
        const int cur = kt & 1;
        const int nb  = cur ^ 1;
        float4 a0, a1;
        if (kt < 7) {               // issue next-tile loads (latency hides
            const int nk = (kt + 1) * 32;   // under the MFMA phase below)
            a0 = *(const float4*)(gA + nk);
            a1 = *(const float4*)(gA + nk + 4);
            gld16(gB0 + nk, lB0 + nb * 8192);
            gld16(gB1 + nk, lB1 + nb * 8192);
        }
        v8s a[4], b[4];
        #pragma unroll
        for (int i = 0; i < 4; ++i)
            a[i] = *(const v8s*)(&As[cur][(wm * 64 + i * 16 + l16) * 32 + rch8]);
        #pragma unroll
        for (int j = 0; j < 4; ++j)
            b[j] = *(const v8s*)(&Bs[cur][(wn * 64 + j * 16 + l16) * 32 + rch8]);
        #pragma unroll
        for (int i = 0; i < 4; ++i)
            #pragma unroll
            for (int j = 0; j < 4; ++j)
                acc[i][j] = __builtin_amdgcn_mfma_f32_16x16x32_bf16(
                    a[i], b[j], acc[i][j], 0, 0, 0);
        if (kt < 7) {               // cvt + write A-next (same kt body)
            union { unsigned short s[8]; int4 v; } ua;
            ua.s[0] = f2bf(a0.x * ascale); ua.s[1] = f2bf(a0.y * ascale);
            ua.s[2] = f2bf(a0.z * ascale); ua.s[3] = f2bf(a0.w * ascale);
            ua.s[4] = f2bf(a1.x * ascale); ua.s[5] = f2bf(a1.y * ascale);
            ua.s[6] = f2bf(a1.z * ascale); ua.s[7] = f2bf(a1.w * ascale);
            *(int4*)(lA + nb * 4096) = ua.v;
        }
        __syncthreads();   // drains gld16 (vmcnt) + ds ops (lgkm)
    }

    #pragma unroll
    for (int i = 0; i < 4; ++i)
        #pragma unroll
        for (int j = 0; j < 4; ++j)
            #pragma unroll
            for (int r = 0; r < 4; ++r) {
                int gm = bm * 128 + wm * 64 + i * 16 + quad * 4 + r;
                int gn = wn * 64 + j * 16 + l16;
                Y[(size_t)gm * 256 + gn] = f2bf(acc[i][j][r]);
            }
}

// ---------------------------------------------------------------------------
// Output GEMM: out[m][n] = sum_k Att[m][k]*Wp[n][k] + bias[n], fp32 store.
// BM=64 -> 544 blocks (kills the 53%-util tail), 256 thr (1M x 4N),
// same 2-phase gld16 + source/read swizzle structure.
// ---------------------------------------------------------------------------
__global__ __launch_bounds__(256) void gemmo_kernel(
    const unsigned short* __restrict__ A,
    const unsigned short* __restrict__ W,
    const float* __restrict__ bias,
    float* __restrict__ out)
{
    const int bm = blockIdx.x;   // 544 tiles of 64 rows

    __shared__ unsigned short As[2][64 * 32];    // 4 KB x2
    __shared__ unsigned short Bs[2][256 * 32];   // 16 KB x2

    const int tid  = threadIdx.x;
    const int lane = tid & 63;
    const int wn   = tid >> 6;     // N quarter
    const int quad = lane >> 4;
    const int l16  = lane & 15;

    // staging: slot t -> row=t>>2, chunk=t&3; 1 gld16 for A, 4 for B
    const int arow  = tid >> 2;               // 0..63
    const int chunk = tid & 3;
    const int cgA   = (chunk ^ ((arow ^ (arow >> 2)) & 3)) * 8;
    const unsigned short* gA = A + (size_t)(bm * 64 + arow) * 256 + cgA;
    const unsigned short* gB = W + (size_t)arow * 256 + cgA;   // + p*64 rows
    unsigned short* lA = &As[0][tid * 8];
    unsigned short* lB = &Bs[0][tid * 8];

    const int rch8 = (quad ^ ((l16 ^ (l16 >> 2)) & 3)) * 8;

    v4f acc[4][4] = {};

    gld16(gA, lA);
    #pragma unroll
    for (int p = 0; p < 4; ++p)
        gld16(gB + (size_t)p * 64 * 256, lB + p * 2048);
    __syncthreads();

    for (int kt = 0; kt < 8; ++kt) {
        const int cur = kt & 1;
        if (kt < 7) {
            const int nk = (kt + 1) * 32;
            const int nb = cur ^ 1;
            gld16(gA + nk, lA + nb * 2048);
            #pragma unroll
            for (int p = 0; p < 4; ++p)
                gld16(gB + (size_t)p * 64 * 256 + nk, lB + nb * 8192 + p * 2048);
        }
        v8s a[4], b[4];
        #pragma unroll
        for (int i = 0; i < 4; ++i)
            a[i] = *(const v8s*)(&As[cur][(i * 16 + l16) * 32 + rch8]);
        #pragma unroll
        for (int j = 0; j < 4; ++j)
            b[j] = *(const v8s*)(&Bs[cur][(wn * 64 + j * 16 + l16) * 32 + rch8]);
        #pragma unroll
        for (int i = 0; i < 4; ++i)
            #pragma unroll
            for (int j = 0; j < 4; ++j)
                acc[i][j] = __builtin_amdgcn_mfma_f32_16x16x32_bf16(
                    a[i], b[j], acc[i][j], 0, 0, 0);
        __syncthreads();
    }

    #pragma unroll
    for (int i = 0; i < 4; ++i)
        #pragma unroll
        for (int j = 0; j < 4; ++j)
            #pragma unroll
            for (int r = 0; r < 4; ++r) {
                int gm = bm * 64 + i * 16 + quad * 4 + r;
                int gn = wn * 64 + j * 16 + l16;
                out[(size_t)gm * 256 + gn] = acc[i][j][r] + bias[gn];
            }
}

// ---------------------------------------------------------------------------
// Fused attention — byte-identical to R6's passing kernel (53.5us, absmax
// 0.00586, FETCH 52.3MB): direct global->LDS staging between double
// barriers, static V scatter from fresh loads, asm-lgkmcnt Ps/Ls fences,
// fexp2, setprio, XCD-grouped flat grid. T14 reg-staged prefetch remains
// QUARANTINED (R4/R5 determinism failures, mechanism unexplained).
// ---------------------------------------------------------------------------
#define VST 136   // Vs stride (16B-aligned rows), XOR-swizzled s-blocks
#define PST 72    // Ps stride: 144B rows, 16B-aligned, 2-way-free

__global__ __launch_bounds__(256) void attn_kernel(
    const unsigned short* __restrict__ Qp,
    const unsigned short* __restrict__ Kp,
    const unsigned short* __restrict__ Vp,
    unsigned short* __restrict__ Att)
{
    // XCD-grouped id mapping: ids {x + 8*qt + 32*k} share bjh = x + 8*k and
    // are congruent mod 8 -> same XCD under round-robin dispatch.
    const int id  = blockIdx.x;            // 0..2175
    const int bjh = (id & 7) | ((id >> 5) << 3);   // 0..543
    const int qt  = (id >> 3) & 3;
    const int h   = bjh & 7;
    const int bj  = bjh >> 3;
    const int j   = bj % 17;
    const int b_  = bj / 17;

    __shared__ unsigned short Ks[128 * 40];    // [s][cd], pad 40   (10.25 KB)
    __shared__ unsigned short Vs[32 * VST];    // [cd][s], swizzled (8.7 KB)
    __shared__ unsigned short Ps[128 * PST];   // [qrow][s-half]    (18.4 KB)
    __shared__ float Ls[128];                  // row sums          (0.5 KB)

    const int tid  = threadIdx.x;
    const int wave = tid >> 6;
    const int lane = tid & 63;
    const int quad = lane >> 4;
    const int l16  = lane & 15;

    const int base0 = b_ * 512 * RST + j * 256 + h * 32;

    // Q fragments straight from global (each wave reads only its own rows)
    v8s qa[2];
    #pragma unroll
    for (int fi = 0; fi < 2; ++fi)
        qa[fi] = *(const v8s*)(
            Qp + base0 + (qt * 128 + wave * 32 + fi * 16 + l16) * RST + quad * 8);

    float lacc[2] = {0.f, 0.f};
    v4f accO[2][2] = {};

    for (int kc = 0; kc < 4; ++kc) {
        __syncthreads();   // protect previous-iteration Ks/Vs reads
        // stage K chunk [128][32], conflict-free writer mapping
        #pragma unroll
        for (int c = 0; c < 2; ++c) {
            int krow = wave * 16 + l16 + c * 64;
            *(int4*)(&Ks[krow * 40 + quad * 8]) = *(const int4*)(
                Kp + base0 + (kc * 128 + krow) * RST + quad * 8);
        }
        // stage V chunk transposed with XOR swizzle:
        // (cd, srow) -> Vs[cd*VST + ((sblk ^ (cd>>3))<<3) + (srow&7)]
        #pragma unroll
        for (int c = 0; c < 2; ++c) {
            int idx  = c * 256 + tid;
            int srow = idx >> 2;
            int cd0  = (idx & 3) << 3;
            int xof  = (((srow >> 3) ^ (cd0 >> 3)) << 3) + (srow & 7);
            union { int4 v; unsigned short s[8]; } u;
            u.v = *(const int4*)(
                Vp + base0 + (kc * 128 + srow) * RST + cd0);
            #pragma unroll
            for (int i = 0; i < 8; ++i)
                Vs[(cd0 + i) * VST + xof] = u.s[i];
        }
        __syncthreads();

        #pragma unroll
        for (int half = 0; half < 2; ++half) {
            // S^T = K @ Q^T; C-layout col=qrow(l16), row=s
            v4f accST[4][2] = {};
            __builtin_amdgcn_s_setprio(1);
            #pragma unroll
            for (int si = 0; si < 4; ++si) {
                v8s kb = *(const v8s*)(&Ks[((half * 4 + si) * 16 + l16) * 40 + quad * 8]);
                #pragma unroll
                for (int fi = 0; fi < 2; ++fi)
                    accST[si][fi] = __builtin_amdgcn_mfma_f32_16x16x32_bf16(
                        kb, qa[fi], accST[si][fi], 0, 0, 0);
            }
            __builtin_amdgcn_s_setprio(0);
            // exp2 (no max-sub), packed b64 P writes, lane-local l accum
            #pragma unroll
            for (int fi = 0; fi < 2; ++fi) {
                int prow = (wave * 32 + fi * 16 + l16) * PST;
                #pragma unroll
                for (int si = 0; si < 4; ++si) {
                    float p0 = fexp2(accST[si][fi][0]);
                    float p1 = fexp2(accST[si][fi][1]);
                    float p2 = fexp2(accST[si][fi][2]);
                    float p3 = fexp2(accST[si][fi][3]);
                    lacc[fi] += (p0 + p1) + (p2 + p3);
                    uint2 pk;
                    pk.x = pkbf(p0, p1);
                    pk.y = pkbf(p2, p3);
                    *(uint2*)(&Ps[prow + si * 16 + quad * 4]) = pk;
                }
            }
            // Ps rows wave-private: drain LDS writes only
            asm volatile("s_waitcnt lgkmcnt(0)" ::: "memory");

            // O += P @ V over this half (ks local 0..1)
            __builtin_amdgcn_s_setprio(1);
            #pragma unroll
            for (int ks = 0; ks < 2; ++ks) {
                v8s pa[2];
                #pragma unroll
                for (int fi = 0; fi < 2; ++fi)
                    pa[fi] = *(const v8s*)(&Ps[(wave * 32 + fi * 16 + l16) * PST +
                                               ks * 32 + quad * 8]);
                #pragma unroll
                for (int nj = 0; nj < 2; ++nj) {
                    int cd  = nj * 16 + l16;
                    int blk = (half * 8 + ks * 4 + quad) ^ (cd >> 3);
                    v8s vb = *(const v8s*)(&Vs[cd * VST + (blk << 3)]);
                    #pragma unroll
                    for (int fi = 0; fi < 2; ++fi)
                        accO[fi][nj] = __builtin_amdgcn_mfma_f32_16x16x32_bf16(
                            pa[fi], vb, accO[fi][nj], 0, 0, 0);
                }
            }
            __builtin_amdgcn_s_setprio(0);
        }
    }

    // final l: reduce lane partials across the 4 quads sharing each qrow
    #pragma unroll
    for (int fi = 0; fi < 2; ++fi) {
        float lv = lacc[fi];
        lv += __shfl_xor(lv, 16);
        lv += __shfl_xor(lv, 32);
        if (quad == 0) Ls[wave * 32 + fi * 16 + l16] = lv;
    }
    asm volatile("s_waitcnt lgkmcnt(0)" ::: "memory");

    // epilogue: Att row-major [(b,t,j)][(h,cd)]
    #pragma unroll
    for (int fi = 0; fi < 2; ++fi) {
        float4 lv = *(float4*)(&Ls[wave * 32 + fi * 16 + quad * 4]);
        float rl[4] = {1.f / lv.x, 1.f / lv.y, 1.f / lv.z, 1.f / lv.w};
        #pragma unroll
        for (int nj = 0; nj < 2; ++nj) {
            #pragma unroll
            for (int r = 0; r < 4; ++r) {
                int trow = qt * 128 + wave * 32 + fi * 16 + quad * 4 + r;
                int cd   = nj * 16 + l16;
                float v  = accO[fi][nj][r] * rl[r];
                Att[(size_t)(base0 + trow * RST + cd)] = f2bf(v);
            }
        }
    }
}

extern "C" void kernel_launch(void* const* d_in, const int* in_sizes, int n_in,
                              void* d_out, int out_size, void* d_ws, size_t ws_size,
                              hipStream_t stream) {
    const float* q  = (const float*)d_in[0];
    const float* kv = (const float*)d_in[1];
    const float* Wq = (const float*)d_in[2];
    const float* Wk = (const float*)d_in[3];
    const float* Wv = (const float*)d_in[4];
    const float* Wp = (const float*)d_in[5];
    const float* bp = (const float*)d_in[6];

    unsigned short* ws  = (unsigned short*)d_ws;
    unsigned short* Qp  = ws;                 // SZE
    unsigned short* Kp  = ws + SZE;           // SZE
    unsigned short* Vp  = ws + 2 * SZE;       // SZE
    unsigned short* Att = ws + 3 * SZE;       // SZE
    unsigned short* Wqb = ws + 4 * SZE;
    unsigned short* Wkb = Wqb + WSZ;
    unsigned short* Wvb = Wkb + WSZ;
    unsigned short* Wpb = Wvb + WSZ;
    float* out = (float*)d_out;

    // 0) weights-only fp32 -> bf16 prep (q/kv conversion fused into GEMM)
    prepw_kernel<<<128, 256, 0, stream>>>(Wq, Wk, Wv, Wp,
                                          Wqb, Wkb, Wvb, Wpb);
    // 1) Q/K/V projections: fp32 A inputs, fused conversion (QSCALE on z=0)
    gemm_kernel<<<dim3(272, 3), 512, 0, stream>>>(
        q, kv, Wqb, Wkb, Wvb, Qp, Kp, Vp);
    // 2) fused attention (XCD-grouped flat grid)
    attn_kernel<<<dim3(2176), 256, 0, stream>>>(Qp, Kp, Vp, Att);
    // 3) output projection + bias (fp32 out), BM=64 tail-friendly grid
    gemmo_kernel<<<dim3(544), 256, 0, stream>>>(Att, Wpb, bp, out);
}